// Round 1
// baseline (554.083 us; speedup 1.0000x reference)
//
#include <hip/hip_runtime.h>
#include <math.h>

// FourierCrossAttention: B=16, L=4096, H=8, E=EO=64, MODES=64 (lowest)
// Stage A: folded truncated DFT of q,k -> Xq,Xk [bh][e][m] complex
// Stage B: xqk = Xq^T Xk (contract e) -> tanh -> xqkv (contract y) -> *(w1+i w2) (contract e) -> XW [bh][m][o]
// Stage C: irfft (64 modes) + transpose to [b][t][h][o], scale 2^-30 total (1/4096 * 1/262144)

constexpr float TWOPI_L = 1.5339807878856412e-3f;  // 2*pi/4096

// ---------------- K1: folded DFT (64 lowest modes) of q and k ----------------
__global__ __launch_bounds__(256) void k1_dft(const float* __restrict__ q,
                                              const float* __restrict__ k,
                                              float* __restrict__ Xq,
                                              float* __restrict__ Xk)
{
    const int src = blockIdx.x >> 7;
    const int bh  = blockIdx.x & 127;
    const int b = bh >> 3, h = bh & 7;
    const float* __restrict__ x = src ? k : q;
    float* __restrict__ X = src ? Xk : Xq;

    __shared__ float xp[64][68];   // x[t] + x[t+2048], padded rows (bank-friendly)
    __shared__ float xm[64][68];   // x[t] - x[t+2048]

    const int tid = threadIdx.x;
    const int m4 = tid & 15;        // modes m4 + 16*j, j=0..3 (uniform parity = m4&1)
    const int e4 = tid >> 4;        // e = e4*4 + i, i=0..3

    // rotation step per mode: angle 2*pi*m/4096
    float cd[4], sd[4];
#pragma unroll
    for (int j = 0; j < 4; ++j) {
        sincosf((float)(m4 + 16*j) * TWOPI_L, &sd[j], &cd[j]);
    }

    float accR[4][4] = {{0.f}}, accI[4][4] = {{0.f}};

    const int srow = tid >> 2;      // staging row 0..63
    const int sq4  = tid & 3;
    const float* gbase = x + (size_t)b * (4096u * 512u) + (size_t)(h * 64 + sq4 * 16);

    for (int ch = 0; ch < 32; ++ch) {
        const int t0 = ch << 6;
        // ---- stage: fold rows t0+r and t0+r+2048 ----
        {
            const float* g0 = gbase + (size_t)(t0 + srow) * 512u;
            const float* g1 = g0 + 2048u * 512u;
#pragma unroll
            for (int i = 0; i < 4; ++i) {
                const float4 a = *(const float4*)(g0 + i * 4);
                const float4 c = *(const float4*)(g1 + i * 4);
                float4 sv, dv;
                sv.x = a.x + c.x; sv.y = a.y + c.y; sv.z = a.z + c.z; sv.w = a.w + c.w;
                dv.x = a.x - c.x; dv.y = a.y - c.y; dv.z = a.z - c.z; dv.w = a.w - c.w;
                *(float4*)&xp[srow][sq4 * 16 + i * 4] = sv;
                *(float4*)&xm[srow][sq4 * 16 + i * 4] = dv;
            }
        }
        __syncthreads();

        // twiddle state at t = t0 for each of the 4 modes
        float cs[4], sn[4];
#pragma unroll
        for (int j = 0; j < 4; ++j) {
            const int m = m4 + 16 * j;
            sincosf((float)((m * t0) & 4095) * TWOPI_L, &sn[j], &cs[j]);
        }
        const float (*__restrict__ xs)[68] = (m4 & 1) ? xm : xp;
#pragma unroll 2
        for (int tt = 0; tt < 64; ++tt) {
            const float4 xv = *(const float4*)&xs[tt][e4 * 4];
#pragma unroll
            for (int j = 0; j < 4; ++j) {
                const float c = cs[j], s = sn[j];
                accR[j][0] += xv.x * c; accI[j][0] -= xv.x * s;
                accR[j][1] += xv.y * c; accI[j][1] -= xv.y * s;
                accR[j][2] += xv.z * c; accI[j][2] -= xv.z * s;
                accR[j][3] += xv.w * c; accI[j][3] -= xv.w * s;
                cs[j] = c * cd[j] - s * sd[j];     // rotate by 2*pi*m/4096
                sn[j] = s * cd[j] + c * sd[j];
            }
        }
        __syncthreads();
    }

    float* Xb = X + (size_t)bh * 8192u;   // [e][m] complex
#pragma unroll
    for (int j = 0; j < 4; ++j) {
#pragma unroll
        for (int i = 0; i < 4; ++i) {
            const int e = e4 * 4 + i;
            const int m = m4 + 16 * j;
            *(float2*)(Xb + (size_t)((e << 6) + m) * 2u) = make_float2(accR[j][i], accI[j][i]);
        }
    }
}

// ---------------- K2: xqk -> tanh -> xqkv -> *w  (one block per bh) ----------------
__global__ __launch_bounds__(256) void k2_mid(const float* __restrict__ Xq,
                                              const float* __restrict__ Xk,
                                              const float* __restrict__ w1,
                                              const float* __restrict__ w2,
                                              float* __restrict__ XW)
{
    const int bh = blockIdx.x;
    const int h = bh & 7;
    __shared__ float smem[12672];        // 50,688 B
    float* sA  = smem;                   // [16][66] complex (2112 floats)
    float* sB  = smem + 2112;            // [16][66] complex
    float* sPK = smem + 4224;            // [64][66] complex (8448 floats)

    const int tid = threadIdx.x;
    const float* Xqb = Xq + (size_t)bh * 8192u;
    const float* Xkb = Xk + (size_t)bh * 8192u;

    const int r  = tid >> 4;   // staging row 0..15
    const int f8 = tid & 15;   // staging 8-float group
    const int tx = tid & 15;   // P1: x = tx + 16*i
    const int ty = tid >> 4;   // P1: y = ty + 16*j

    // ---- P1: xqk[x][y] = sum_e Xq[e][x]*Xk[e][y] ----
    float aR[4][4] = {{0.f}}, aI[4][4] = {{0.f}};
    for (int ch = 0; ch < 4; ++ch) {
        {
            const float* gq = Xqb + (size_t)((ch * 16 + r) * 128 + f8 * 8);
            const float* gk = Xkb + (size_t)((ch * 16 + r) * 128 + f8 * 8);
            float* dA = sA + r * 132 + f8 * 8;
            float* dB = sB + r * 132 + f8 * 8;
            *(float4*)dA       = *(const float4*)gq;
            *(float4*)(dA + 4) = *(const float4*)(gq + 4);
            *(float4*)dB       = *(const float4*)gk;
            *(float4*)(dB + 4) = *(const float4*)(gk + 4);
        }
        __syncthreads();
        for (int er = 0; er < 16; ++er) {
            float2 qx[4], ky[4];
#pragma unroll
            for (int i = 0; i < 4; ++i) qx[i] = *(const float2*)(sA + er * 132 + (tx + 16 * i) * 2);
#pragma unroll
            for (int j = 0; j < 4; ++j) ky[j] = *(const float2*)(sB + er * 132 + (ty + 16 * j) * 2);
#pragma unroll
            for (int i = 0; i < 4; ++i)
#pragma unroll
                for (int j = 0; j < 4; ++j) {
                    aR[i][j] += qx[i].x * ky[j].x - qx[i].y * ky[j].y;
                    aI[i][j] += qx[i].x * ky[j].y + qx[i].y * ky[j].x;
                }
        }
        __syncthreads();
    }
    // tanh and store PK[x][y]
#pragma unroll
    for (int i = 0; i < 4; ++i)
#pragma unroll
        for (int j = 0; j < 4; ++j) {
            const int xx = tx + 16 * i, yy = ty + 16 * j;
            *(float2*)(sPK + xx * 132 + yy * 2) = make_float2(tanhf(aR[i][j]), tanhf(aI[i][j]));
        }
    __syncthreads();

    // ---- P3+P4 per e-chunk ----
    float wR[4][4] = {{0.f}}, wI[4][4] = {{0.f}};   // [o-idx i][x-idx j]
    const int x16 = tid & 15, eo = tid >> 4;        // P3 mapping
    const int xg = tid & 15, og = tid >> 4;         // P4 mapping: x = 4*xg + j, o = og + 16*i
    for (int ch = 0; ch < 4; ++ch) {
        {   // stage LK chunk into sA
            const float* gk = Xkb + (size_t)((ch * 16 + r) * 128 + f8 * 8);
            float* dA = sA + r * 132 + f8 * 8;
            *(float4*)dA       = *(const float4*)gk;
            *(float4*)(dA + 4) = *(const float4*)(gk + 4);
        }
        __syncthreads();
        // P3: PV[eo][x16+16i] = sum_y PK[x][y]*LK[eo][y]
        {
            float pvR[4] = {0.f, 0.f, 0.f, 0.f}, pvI[4] = {0.f, 0.f, 0.f, 0.f};
            for (int y = 0; y < 64; ++y) {
                const float2 kv = *(const float2*)(sA + eo * 132 + y * 2);
#pragma unroll
                for (int i = 0; i < 4; ++i) {
                    const float2 p = *(const float2*)(sPK + (x16 + 16 * i) * 132 + y * 2);
                    pvR[i] += p.x * kv.x - p.y * kv.y;
                    pvI[i] += p.x * kv.y + p.y * kv.x;
                }
            }
#pragma unroll
            for (int i = 0; i < 4; ++i)
                *(float2*)(sB + eo * 132 + (x16 + 16 * i) * 2) = make_float2(pvR[i], pvI[i]);
        }
        __syncthreads();
        // P4: wacc[o][x] += sum_{e in chunk} PV[e][x] * (w1 + i*w2)[h][e][o][x]
        for (int el = 0; el < 16; ++el) {
            const int e = ch * 16 + el;
            float2 pv[4];
#pragma unroll
            for (int jp = 0; jp < 2; ++jp) {
                const float4 t = *(const float4*)(sB + el * 132 + xg * 8 + jp * 4);
                pv[2 * jp]     = make_float2(t.x, t.y);
                pv[2 * jp + 1] = make_float2(t.z, t.w);
            }
            const float* w1p = w1 + (size_t)(((h * 64 + e) * 64 + og) * 64 + xg * 4);
            const float* w2p = w2 + (size_t)(((h * 64 + e) * 64 + og) * 64 + xg * 4);
#pragma unroll
            for (int i = 0; i < 4; ++i) {
                const float4 w1v = *(const float4*)(w1p + i * 1024);
                const float4 w2v = *(const float4*)(w2p + i * 1024);
                const float w1a[4] = {w1v.x, w1v.y, w1v.z, w1v.w};
                const float w2a[4] = {w2v.x, w2v.y, w2v.z, w2v.w};
#pragma unroll
                for (int j = 0; j < 4; ++j) {
                    wR[i][j] += pv[j].x * w1a[j] - pv[j].y * w2a[j];
                    wI[i][j] += pv[j].x * w2a[j] + pv[j].y * w1a[j];
                }
            }
        }
        __syncthreads();
    }
    // write XW [bh][m=x][o]
    float* XWb = XW + (size_t)bh * 8192u;
#pragma unroll
    for (int i = 0; i < 4; ++i)
#pragma unroll
        for (int j = 0; j < 4; ++j) {
            const int o = og + 16 * i, xx = xg * 4 + j;
            *(float2*)(XWb + (size_t)(xx * 64 + o) * 2u) = make_float2(wR[i][j], wI[i][j]);
        }
}

// ---------------- K3: irfft (64 modes) + transpose + scale ----------------
__global__ __launch_bounds__(256) void k3_irfft(const float* __restrict__ XW,
                                                float* __restrict__ out)
{
    const int blk = blockIdx.x;
    const int bh = blk >> 5, chunk = blk & 31;
    const int b = bh >> 3, h = bh & 7;
    __shared__ float sX[64 * 132];           // [m][66 complex], padded

    const float* XWb = XW + (size_t)bh * 8192u;
    const int tid = threadIdx.x;
#pragma unroll
    for (int p = 0; p < 8; ++p) {
        const int f4 = tid + 256 * p;        // 0..2047 float4s
        const int m = f4 >> 5;
        const float4 v = *(const float4*)(XWb + (size_t)f4 * 4u);
        *(float4*)(sX + m * 132 + (f4 & 31) * 4) = v;
    }
    __syncthreads();

    const int og = tid & 7;                  // o pairs: og*2 + {0,1} + 16*p
    const int tpart = tid >> 3;              // 0..31
    const int tb = chunk * 128 + tpart;      // t = tb + 32*ti

    float c[4], s[4], cd[4], sd[4];
#pragma unroll
    for (int ti = 0; ti < 4; ++ti) {
        sincosf((float)(tb + 32 * ti) * TWOPI_L, &sd[ti], &cd[ti]);
        c[ti] = cd[ti]; s[ti] = sd[ti];      // state for m=1
    }

    float acc[4][8];
    {   // DC: 0.5*Re(X0), Im ignored (pocketfft c2r convention)
#pragma unroll
        for (int p = 0; p < 4; ++p) {
            const float4 rd = *(const float4*)(sX + og * 4 + p * 32);
#pragma unroll
            for (int ti = 0; ti < 4; ++ti) {
                acc[ti][2 * p]     = 0.5f * rd.x;
                acc[ti][2 * p + 1] = 0.5f * rd.z;
            }
        }
    }
    for (int m = 1; m < 64; ++m) {
#pragma unroll
        for (int p = 0; p < 4; ++p) {
            const float4 rd = *(const float4*)(sX + m * 132 + og * 4 + p * 32);
#pragma unroll
            for (int ti = 0; ti < 4; ++ti) {
                acc[ti][2 * p]     += c[ti] * rd.x - s[ti] * rd.y;
                acc[ti][2 * p + 1] += c[ti] * rd.z - s[ti] * rd.w;
            }
        }
#pragma unroll
        for (int ti = 0; ti < 4; ++ti) {
            const float nc = c[ti] * cd[ti] - s[ti] * sd[ti];
            s[ti] = s[ti] * cd[ti] + c[ti] * sd[ti];
            c[ti] = nc;
        }
    }
    const float scale = 1.862645149230957e-9f;  // 2 * (1/4096) * (1/262144) = 2^-29
#pragma unroll
    for (int ti = 0; ti < 4; ++ti) {
        const int t = tb + 32 * ti;
        float* ob = out + ((size_t)(b * 4096 + t) * 8 + (size_t)h) * 64u;
#pragma unroll
        for (int p = 0; p < 4; ++p) {
            *(float2*)(ob + og * 2 + p * 16) =
                make_float2(acc[ti][2 * p] * scale, acc[ti][2 * p + 1] * scale);
        }
    }
}

extern "C" void kernel_launch(void* const* d_in, const int* in_sizes, int n_in,
                              void* d_out, int out_size, void* d_ws, size_t ws_size,
                              hipStream_t stream) {
    (void)in_sizes; (void)n_in; (void)out_size; (void)ws_size;
    const float* q  = (const float*)d_in[0];
    const float* k  = (const float*)d_in[1];
    // d_in[2] = v: unused by the reference forward
    const float* w1 = (const float*)d_in[3];
    const float* w2 = (const float*)d_in[4];
    float* out = (float*)d_out;

    float* ws = (float*)d_ws;
    float* Xq = ws;                    // 1,048,576 floats
    float* Xk = ws + 1048576;          // 1,048,576 floats
    float* XW = ws + 2097152;          // 1,048,576 floats  (12 MB total)

    hipLaunchKernelGGL(k1_dft,   dim3(256),  dim3(256), 0, stream, q, k, Xq, Xk);
    hipLaunchKernelGGL(k2_mid,   dim3(128),  dim3(256), 0, stream, Xq, Xk, w1, w2, XW);
    hipLaunchKernelGGL(k3_irfft, dim3(4096), dim3(256), 0, stream, XW, out);
}

// Round 2
// 360.285 us; speedup vs baseline: 1.5379x; 1.5379x over previous
//
#include <hip/hip_runtime.h>
#include <math.h>

// FourierCrossAttention: B=16, L=4096, H=8, E=EO=64, MODES=64 (lowest)
// R2: Stage A (truncated DFT) moved to MFMA split-bf16 (hi/lo, 3 passes).
//   k0: twiddle hi/lo tables [128 m'-rows x 4096 t] bf16 (rows: 2m=cos, 2m+1=-sin)
//   k1: batched GEMM X[128 x 64e] = W[128 x 2048] * x[2048 x 64], K-split S=2
//   k1b: partial reduce
//   k2/k3: unchanged fp32 VALU (stage B tiny; stage C next round)

constexpr float TWOPI_L = 1.5339807878856412e-3f;  // 2*pi/4096

typedef __attribute__((ext_vector_type(8))) short short8;
typedef __attribute__((ext_vector_type(4))) float f32x4;

__device__ __forceinline__ unsigned short f2bf(float f) {
    unsigned int u = __builtin_bit_cast(unsigned int, f);
    unsigned int r = (u + 0x7fffu + ((u >> 16) & 1u)) >> 16;
    return (unsigned short)r;
}
__device__ __forceinline__ float bf2f(unsigned short h) {
    unsigned int u = ((unsigned int)h) << 16;
    return __builtin_bit_cast(float, u);
}

// ---------------- K0: twiddle table gen (hi/lo bf16) ----------------
__global__ __launch_bounds__(256) void k0_twiddle(unsigned short* __restrict__ Whi,
                                                  unsigned short* __restrict__ Wlo) {
    const int idx = blockIdx.x * 256 + threadIdx.x;   // 131072 threads
    const int r = idx >> 10;            // 0..127
    const int t4 = (idx & 1023) << 2;   // 0..4092
    const int m = r >> 1;
    const bool isim = (r & 1) != 0;
#pragma unroll
    for (int j = 0; j < 4; ++j) {
        const int t = t4 + j;
        float sv, cv;
        sincosf((float)((m * t) & 4095) * TWOPI_L, &sv, &cv);
        const float v = isim ? -sv : cv;
        const unsigned short hi = f2bf(v);
        const unsigned short lo = f2bf(v - bf2f(hi));
        Whi[r * 4096 + t] = hi;
        Wlo[r * 4096 + t] = lo;
    }
}

// ---------------- K1: MFMA DFT  C[128 rows][64 e] over K=2048 per block ----------------
__global__ __launch_bounds__(256) void k1_mfma(const float* __restrict__ q,
                                               const float* __restrict__ kin,
                                               const unsigned short* __restrict__ Whi,
                                               const unsigned short* __restrict__ Wlo,
                                               float* __restrict__ Xq, float* __restrict__ Xk,
                                               float* __restrict__ Pq, float* __restrict__ Pk)
{
    __shared__ unsigned short xTh[2][64][72];   // [buf][e][k pad 64+8] hi, 144B rows (16B-aligned)
    __shared__ unsigned short xTl[2][64][72];   // lo

    const int tid = threadIdx.x;
    const int bid = blockIdx.x;
    const int bh = bid >> 2, src = (bid >> 1) & 1, seg = bid & 1;
    const int b = bh >> 3, h = bh & 7;
    const float* __restrict__ x = src ? kin : q;
    const float* xb = x + (size_t)b * 2097152u + (size_t)h * 64u + (size_t)(seg * 2048) * 512u;

    // staging: thread handles t-pair tp,tp+1 and e-octet e0..e0+7
    const int tp = (tid & 31) * 2;
    const int e0 = (tid >> 5) * 8;

    const int wid = tid >> 6, lane = tid & 63;
    const int l15 = lane & 15, lg = lane >> 4;

    // A (twiddle) per-lane global element offset: row = wid*32 + mt*16 + l15, k-base 8*lg
    const size_t aOff = (size_t)(wid * 32 + l15) * 4096u + (size_t)(seg * 2048) + (size_t)(8 * lg);

    f32x4 acc[2][4];
#pragma unroll
    for (int mt = 0; mt < 2; ++mt)
#pragma unroll
        for (int nt = 0; nt < 4; ++nt)
            acc[mt][nt] = (f32x4){0.f, 0.f, 0.f, 0.f};

    float rs[16];
    // prologue: stage tile 0 into buf 0
    {
        const float* r0 = xb + (size_t)tp * 512u + e0;
        *(float4*)&rs[0]  = *(const float4*)r0;
        *(float4*)&rs[4]  = *(const float4*)(r0 + 4);
        *(float4*)&rs[8]  = *(const float4*)(r0 + 512);
        *(float4*)&rs[12] = *(const float4*)(r0 + 516);
    }
#pragma unroll
    for (int e = 0; e < 8; ++e) {
        const unsigned short h0 = f2bf(rs[e]), h1 = f2bf(rs[8 + e]);
        const unsigned short l0 = f2bf(rs[e] - bf2f(h0)), l1 = f2bf(rs[8 + e] - bf2f(h1));
        *(unsigned int*)&xTh[0][e0 + e][tp] = (unsigned int)h0 | ((unsigned int)h1 << 16);
        *(unsigned int*)&xTl[0][e0 + e][tp] = (unsigned int)l0 | ((unsigned int)l1 << 16);
    }
    __syncthreads();

    int cur = 0;
    for (int it = 0; it < 32; ++it) {
        // issue next tile's global loads early (hide HBM latency under MFMA)
        if (it + 1 < 32) {
            const float* r0 = xb + (size_t)((it + 1) * 64 + tp) * 512u + e0;
            *(float4*)&rs[0]  = *(const float4*)r0;
            *(float4*)&rs[4]  = *(const float4*)(r0 + 4);
            *(float4*)&rs[8]  = *(const float4*)(r0 + 512);
            *(float4*)&rs[12] = *(const float4*)(r0 + 516);
        }
        // MFMA on buf cur: two K32 steps
#pragma unroll
        for (int ks = 0; ks < 2; ++ks) {
            const int koff = it * 64 + ks * 32;
            short8 Ah[2], Al[2];
#pragma unroll
            for (int mt = 0; mt < 2; ++mt) {
                Ah[mt] = *(const short8*)(Whi + aOff + (size_t)(mt * 16) * 4096u + koff);
                Al[mt] = *(const short8*)(Wlo + aOff + (size_t)(mt * 16) * 4096u + koff);
            }
            short8 Bh[4], Bl[4];
            const unsigned short* sh = &xTh[cur][0][0];
            const unsigned short* sl = &xTl[cur][0][0];
#pragma unroll
            for (int nt = 0; nt < 4; ++nt) {
                const int ri = (nt * 16 + l15) * 72 + 8 * lg + ks * 32;
                Bh[nt] = *(const short8*)(sh + ri);
                Bl[nt] = *(const short8*)(sl + ri);
            }
#pragma unroll
            for (int mt = 0; mt < 2; ++mt)
#pragma unroll
                for (int nt = 0; nt < 4; ++nt)
                    acc[mt][nt] = __builtin_amdgcn_mfma_f32_16x16x32_bf16(Ah[mt], Bh[nt], acc[mt][nt], 0, 0, 0);
#pragma unroll
            for (int mt = 0; mt < 2; ++mt)
#pragma unroll
                for (int nt = 0; nt < 4; ++nt)
                    acc[mt][nt] = __builtin_amdgcn_mfma_f32_16x16x32_bf16(Ah[mt], Bl[nt], acc[mt][nt], 0, 0, 0);
#pragma unroll
            for (int mt = 0; mt < 2; ++mt)
#pragma unroll
                for (int nt = 0; nt < 4; ++nt)
                    acc[mt][nt] = __builtin_amdgcn_mfma_f32_16x16x32_bf16(Al[mt], Bh[nt], acc[mt][nt], 0, 0, 0);
        }
        // convert + write next tile into the other buffer
        if (it + 1 < 32) {
            const int nxt = cur ^ 1;
#pragma unroll
            for (int e = 0; e < 8; ++e) {
                const unsigned short h0 = f2bf(rs[e]), h1 = f2bf(rs[8 + e]);
                const unsigned short l0 = f2bf(rs[e] - bf2f(h0)), l1 = f2bf(rs[8 + e] - bf2f(h1));
                *(unsigned int*)&xTh[nxt][e0 + e][tp] = (unsigned int)h0 | ((unsigned int)h1 << 16);
                *(unsigned int*)&xTl[nxt][e0 + e][tp] = (unsigned int)l0 | ((unsigned int)l1 << 16);
            }
        }
        __syncthreads();
        cur ^= 1;
    }

    // C-write: lane (l15,lg) frag (mt,nt): col e = nt*16+l15, rows r0..r0+3
    // rows interleave (Re m, Im m): row r -> X[e][r] float; float4 per frag.
    float* Xd = (seg == 0) ? (src ? Xk : Xq) : (src ? Pk : Pq);
    Xd += (size_t)bh * 8192u;
#pragma unroll
    for (int mt = 0; mt < 2; ++mt)
#pragma unroll
        for (int nt = 0; nt < 4; ++nt) {
            const int e = nt * 16 + l15;
            const int r0 = wid * 32 + mt * 16 + 4 * lg;
            *(float4*)(Xd + (size_t)e * 128u + r0) = *(float4*)&acc[mt][nt];
        }
}

// ---------------- K1b: reduce K-split partials ----------------
__global__ __launch_bounds__(256) void k1_reduce(float* __restrict__ Xq, const float* __restrict__ Pq,
                                                 float* __restrict__ Xk, const float* __restrict__ Pk) {
    const int i = blockIdx.x * 256 + threadIdx.x;   // 262144 float4s per array
    float4* a = (float4*)Xq; const float4* pa = (const float4*)Pq;
    float4* c = (float4*)Xk; const float4* pc = (const float4*)Pk;
    float4 v = a[i]; const float4 p = pa[i];
    v.x += p.x; v.y += p.y; v.z += p.z; v.w += p.w;
    a[i] = v;
    float4 w = c[i]; const float4 r = pc[i];
    w.x += r.x; w.y += r.y; w.z += r.z; w.w += r.w;
    c[i] = w;
}

// ---------------- K2: xqk -> tanh -> xqkv -> *w  (one block per bh) ----------------
__global__ __launch_bounds__(256) void k2_mid(const float* __restrict__ Xq,
                                              const float* __restrict__ Xk,
                                              const float* __restrict__ w1,
                                              const float* __restrict__ w2,
                                              float* __restrict__ XW)
{
    const int bh = blockIdx.x;
    const int h = bh & 7;
    __shared__ float smem[12672];        // 50,688 B
    float* sA  = smem;                   // [16][66] complex (2112 floats)
    float* sB  = smem + 2112;            // [16][66] complex
    float* sPK = smem + 4224;            // [64][66] complex (8448 floats)

    const int tid = threadIdx.x;
    const float* Xqb = Xq + (size_t)bh * 8192u;
    const float* Xkb = Xk + (size_t)bh * 8192u;

    const int r  = tid >> 4;   // staging row 0..15
    const int f8 = tid & 15;   // staging 8-float group
    const int tx = tid & 15;   // P1: x = tx + 16*i
    const int ty = tid >> 4;   // P1: y = ty + 16*j

    // ---- P1: xqk[x][y] = sum_e Xq[e][x]*Xk[e][y] ----
    float aR[4][4] = {{0.f}}, aI[4][4] = {{0.f}};
    for (int ch = 0; ch < 4; ++ch) {
        {
            const float* gq = Xqb + (size_t)((ch * 16 + r) * 128 + f8 * 8);
            const float* gk = Xkb + (size_t)((ch * 16 + r) * 128 + f8 * 8);
            float* dA = sA + r * 132 + f8 * 8;
            float* dB = sB + r * 132 + f8 * 8;
            *(float4*)dA       = *(const float4*)gq;
            *(float4*)(dA + 4) = *(const float4*)(gq + 4);
            *(float4*)dB       = *(const float4*)gk;
            *(float4*)(dB + 4) = *(const float4*)(gk + 4);
        }
        __syncthreads();
        for (int er = 0; er < 16; ++er) {
            float2 qx[4], ky[4];
#pragma unroll
            for (int i = 0; i < 4; ++i) qx[i] = *(const float2*)(sA + er * 132 + (tx + 16 * i) * 2);
#pragma unroll
            for (int j = 0; j < 4; ++j) ky[j] = *(const float2*)(sB + er * 132 + (ty + 16 * j) * 2);
#pragma unroll
            for (int i = 0; i < 4; ++i)
#pragma unroll
                for (int j = 0; j < 4; ++j) {
                    aR[i][j] += qx[i].x * ky[j].x - qx[i].y * ky[j].y;
                    aI[i][j] += qx[i].x * ky[j].y + qx[i].y * ky[j].x;
                }
        }
        __syncthreads();
    }
    // tanh and store PK[x][y]
#pragma unroll
    for (int i = 0; i < 4; ++i)
#pragma unroll
        for (int j = 0; j < 4; ++j) {
            const int xx = tx + 16 * i, yy = ty + 16 * j;
            *(float2*)(sPK + xx * 132 + yy * 2) = make_float2(tanhf(aR[i][j]), tanhf(aI[i][j]));
        }
    __syncthreads();

    // ---- P3+P4 per e-chunk ----
    float wR[4][4] = {{0.f}}, wI[4][4] = {{0.f}};   // [o-idx i][x-idx j]
    const int x16 = tid & 15, eo = tid >> 4;        // P3 mapping
    const int xg = tid & 15, og = tid >> 4;         // P4 mapping: x = 4*xg + j, o = og + 16*i
    for (int ch = 0; ch < 4; ++ch) {
        {   // stage LK chunk into sA
            const float* gk = Xkb + (size_t)((ch * 16 + r) * 128 + f8 * 8);
            float* dA = sA + r * 132 + f8 * 8;
            *(float4*)dA       = *(const float4*)gk;
            *(float4*)(dA + 4) = *(const float4*)(gk + 4);
        }
        __syncthreads();
        // P3: PV[eo][x16+16i] = sum_y PK[x][y]*LK[eo][y]
        {
            float pvR[4] = {0.f, 0.f, 0.f, 0.f}, pvI[4] = {0.f, 0.f, 0.f, 0.f};
            for (int y = 0; y < 64; ++y) {
                const float2 kv = *(const float2*)(sA + eo * 132 + y * 2);
#pragma unroll
                for (int i = 0; i < 4; ++i) {
                    const float2 p = *(const float2*)(sPK + (x16 + 16 * i) * 132 + y * 2);
                    pvR[i] += p.x * kv.x - p.y * kv.y;
                    pvI[i] += p.x * kv.y + p.y * kv.x;
                }
            }
#pragma unroll
            for (int i = 0; i < 4; ++i)
                *(float2*)(sB + eo * 132 + (x16 + 16 * i) * 2) = make_float2(pvR[i], pvI[i]);
        }
        __syncthreads();
        // P4: wacc[o][x] += sum_{e in chunk} PV[e][x] * (w1 + i*w2)[h][e][o][x]
        for (int el = 0; el < 16; ++el) {
            const int e = ch * 16 + el;
            float2 pv[4];
#pragma unroll
            for (int jp = 0; jp < 2; ++jp) {
                const float4 t = *(const float4*)(sB + el * 132 + xg * 8 + jp * 4);
                pv[2 * jp]     = make_float2(t.x, t.y);
                pv[2 * jp + 1] = make_float2(t.z, t.w);
            }
            const float* w1p = w1 + (size_t)(((h * 64 + e) * 64 + og) * 64 + xg * 4);
            const float* w2p = w2 + (size_t)(((h * 64 + e) * 64 + og) * 64 + xg * 4);
#pragma unroll
            for (int i = 0; i < 4; ++i) {
                const float4 w1v = *(const float4*)(w1p + i * 1024);
                const float4 w2v = *(const float4*)(w2p + i * 1024);
                const float w1a[4] = {w1v.x, w1v.y, w1v.z, w1v.w};
                const float w2a[4] = {w2v.x, w2v.y, w2v.z, w2v.w};
#pragma unroll
                for (int j = 0; j < 4; ++j) {
                    wR[i][j] += pv[j].x * w1a[j] - pv[j].y * w2a[j];
                    wI[i][j] += pv[j].x * w2a[j] + pv[j].y * w1a[j];
                }
            }
        }
        __syncthreads();
    }
    // write XW [bh][m=x][o]
    float* XWb = XW + (size_t)bh * 8192u;
#pragma unroll
    for (int i = 0; i < 4; ++i)
#pragma unroll
        for (int j = 0; j < 4; ++j) {
            const int o = og + 16 * i, xx = xg * 4 + j;
            *(float2*)(XWb + (size_t)(xx * 64 + o) * 2u) = make_float2(wR[i][j], wI[i][j]);
        }
}

// ---------------- K3: irfft (64 modes) + transpose + scale ----------------
__global__ __launch_bounds__(256) void k3_irfft(const float* __restrict__ XW,
                                                float* __restrict__ out)
{
    const int blk = blockIdx.x;
    const int bh = blk >> 5, chunk = blk & 31;
    const int b = bh >> 3, h = bh & 7;
    __shared__ float sX[64 * 132];           // [m][66 complex], padded

    const float* XWb = XW + (size_t)bh * 8192u;
    const int tid = threadIdx.x;
#pragma unroll
    for (int p = 0; p < 8; ++p) {
        const int f4 = tid + 256 * p;        // 0..2047 float4s
        const int m = f4 >> 5;
        const float4 v = *(const float4*)(XWb + (size_t)f4 * 4u);
        *(float4*)(sX + m * 132 + (f4 & 31) * 4) = v;
    }
    __syncthreads();

    const int og = tid & 7;                  // o pairs: og*2 + {0,1} + 16*p
    const int tpart = tid >> 3;              // 0..31
    const int tb = chunk * 128 + tpart;      // t = tb + 32*ti

    float c[4], s[4], cd[4], sd[4];
#pragma unroll
    for (int ti = 0; ti < 4; ++ti) {
        sincosf((float)(tb + 32 * ti) * TWOPI_L, &sd[ti], &cd[ti]);
        c[ti] = cd[ti]; s[ti] = sd[ti];      // state for m=1
    }

    float acc[4][8];
    {   // DC: 0.5*Re(X0), Im ignored (pocketfft c2r convention)
#pragma unroll
        for (int p = 0; p < 4; ++p) {
            const float4 rd = *(const float4*)(sX + og * 4 + p * 32);
#pragma unroll
            for (int ti = 0; ti < 4; ++ti) {
                acc[ti][2 * p]     = 0.5f * rd.x;
                acc[ti][2 * p + 1] = 0.5f * rd.z;
            }
        }
    }
    for (int m = 1; m < 64; ++m) {
#pragma unroll
        for (int p = 0; p < 4; ++p) {
            const float4 rd = *(const float4*)(sX + m * 132 + og * 4 + p * 32);
#pragma unroll
            for (int ti = 0; ti < 4; ++ti) {
                acc[ti][2 * p]     += c[ti] * rd.x - s[ti] * rd.y;
                acc[ti][2 * p + 1] += c[ti] * rd.z - s[ti] * rd.w;
            }
        }
#pragma unroll
        for (int ti = 0; ti < 4; ++ti) {
            const float nc = c[ti] * cd[ti] - s[ti] * sd[ti];
            s[ti] = s[ti] * cd[ti] + c[ti] * sd[ti];
            c[ti] = nc;
        }
    }
    const float scale = 1.862645149230957e-9f;  // 2 * (1/4096) * (1/262144) = 2^-29
#pragma unroll
    for (int ti = 0; ti < 4; ++ti) {
        const int t = tb + 32 * ti;
        float* ob = out + ((size_t)(b * 4096 + t) * 8 + (size_t)h) * 64u;
#pragma unroll
        for (int p = 0; p < 4; ++p) {
            *(float2*)(ob + og * 2 + p * 16) =
                make_float2(acc[ti][2 * p] * scale, acc[ti][2 * p + 1] * scale);
        }
    }
}

extern "C" void kernel_launch(void* const* d_in, const int* in_sizes, int n_in,
                              void* d_out, int out_size, void* d_ws, size_t ws_size,
                              hipStream_t stream) {
    (void)in_sizes; (void)n_in; (void)out_size; (void)ws_size;
    const float* q  = (const float*)d_in[0];
    const float* k  = (const float*)d_in[1];
    // d_in[2] = v: unused by the reference forward
    const float* w1 = (const float*)d_in[3];
    const float* w2 = (const float*)d_in[4];
    float* out = (float*)d_out;

    float* ws = (float*)d_ws;
    float* Xq = ws;                    // 1,048,576 floats
    float* Xk = ws + 1048576;          // 1,048,576 floats
    float* XW = ws + 2097152;          // 1,048,576 floats  (12 MB total, as R1)

    // d_out used as scratch before k3 fully overwrites it:
    //   twiddle tables in floats [0, 524288); K-split partials at [1M, 3M)
    unsigned short* Whi = (unsigned short*)out;         // 524288 bf16
    unsigned short* Wlo = Whi + 524288;                 // 524288 bf16
    float* Pq = out + 1048576;
    float* Pk = out + 2097152;

    hipLaunchKernelGGL(k0_twiddle, dim3(512),  dim3(256), 0, stream, Whi, Wlo);
    hipLaunchKernelGGL(k1_mfma,    dim3(512),  dim3(256), 0, stream, q, k, Whi, Wlo, Xq, Xk, Pq, Pk);
    hipLaunchKernelGGL(k1_reduce,  dim3(1024), dim3(256), 0, stream, Xq, Pq, Xk, Pk);
    hipLaunchKernelGGL(k2_mid,     dim3(128),  dim3(256), 0, stream, Xq, Xk, w1, w2, XW);
    hipLaunchKernelGGL(k3_irfft,   dim3(4096), dim3(256), 0, stream, XW, out);
}

// Round 3
// 358.150 us; speedup vs baseline: 1.5471x; 1.0060x over previous
//
#include <hip/hip_runtime.h>
#include <math.h>

// FourierCrossAttention: B=16, L=4096, H=8, E=EO=64, MODES=64 (lowest)
// R3: k1 occupancy+convert fix (S=4, single-buf, v_cvt_pk_bf16_f32);
//     k3 -> MFMA (basis-hi x (XWhi+XWlo), 2-pass), basis generated into ws
//     after k2 frees Xq (no new ws-size assumptions; ws stays 12 MB).

constexpr float TWOPI_L = 1.5339807878856412e-3f;  // 2*pi/4096

typedef __attribute__((ext_vector_type(8))) short short8;
typedef __attribute__((ext_vector_type(4))) float f32x4;

__device__ __forceinline__ unsigned short f2bf(float f) {
    unsigned int u = __builtin_bit_cast(unsigned int, f);
    unsigned int r = (u + 0x7fffu + ((u >> 16) & 1u)) >> 16;
    return (unsigned short)r;
}
__device__ __forceinline__ float bf2f(unsigned short h) {
    unsigned int u = ((unsigned int)h) << 16;
    return __builtin_bit_cast(float, u);
}
// packed RNE f32->bf16 pair: low16 = bf(a), high16 = bf(b)
__device__ __forceinline__ unsigned int cvtpk(float a, float b) {
    unsigned int r;
    asm("v_cvt_pk_bf16_f32 %0, %1, %2" : "=v"(r) : "v"(a), "v"(b));
    return r;
}

// ---------------- K0: DFT twiddle tables (hi/lo bf16) ----------------
__global__ __launch_bounds__(256) void k0_twiddle(unsigned short* __restrict__ Whi,
                                                  unsigned short* __restrict__ Wlo) {
    const int idx = blockIdx.x * 256 + threadIdx.x;   // 131072 threads
    const int r = idx >> 10;            // 0..127
    const int t4 = (idx & 1023) << 2;   // 0..4092
    const int m = r >> 1;
    const bool isim = (r & 1) != 0;
#pragma unroll
    for (int j = 0; j < 4; ++j) {
        const int t = t4 + j;
        float sv, cv;
        sincosf((float)((m * t) & 4095) * TWOPI_L, &sv, &cv);
        const float v = isim ? -sv : cv;
        const unsigned short hi = f2bf(v);
        const unsigned short lo = f2bf(v - bf2f(hi));
        Whi[r * 4096 + t] = hi;
        Wlo[r * 4096 + t] = lo;
    }
}

// ---------------- K0b: irfft basis (bf16 hi only), written into ws (ex-Xq) ----------------
// basis[t][2m] = 2*cos(2*pi*m*t/L), basis[t][2m+1] = -2*sin(...); m=0: (1, 0)
__global__ __launch_bounds__(256) void k0_basis(unsigned short* __restrict__ basis) {
    const int idx = blockIdx.x * 256 + threadIdx.x;   // 65536 threads x 4 pairs
    const int p0 = idx << 2;                          // (t,m) pair index
    const int t = p0 >> 6;
    unsigned int pk[4];
#pragma unroll
    for (int j = 0; j < 4; ++j) {
        const int m = (p0 & 63) + j;
        float sv, cv;
        sincosf((float)((m * t) & 4095) * TWOPI_L, &sv, &cv);
        const float c = (m == 0) ? 1.0f : 2.0f * cv;
        const float s = (m == 0) ? 0.0f : -2.0f * sv;
        pk[j] = (unsigned int)f2bf(c) | ((unsigned int)f2bf(s) << 16);
    }
    *(uint4*)(basis + (size_t)t * 128u + ((p0 & 63) << 1)) =
        make_uint4(pk[0], pk[1], pk[2], pk[3]);
}

// ---------------- K1: MFMA DFT  C[128 rows][64 e], K=1024 per block (S=4) ----------------
__global__ __launch_bounds__(256, 3) void k1_mfma(const float* __restrict__ q,
                                                  const float* __restrict__ kin,
                                                  const unsigned short* __restrict__ Whi,
                                                  const unsigned short* __restrict__ Wlo,
                                                  float* __restrict__ Xq, float* __restrict__ Xk,
                                                  float* __restrict__ Pq, float* __restrict__ Pk)
{
    __shared__ unsigned short xTh[64][72];   // [e][k pad 64+8] hi, single buffer
    __shared__ unsigned short xTl[64][72];   // lo   (36,864 B total)

    const int tid = threadIdx.x;
    const int bid = blockIdx.x;
    const int bh = bid >> 3, src = (bid >> 2) & 1, seg = bid & 3;
    const int b = bh >> 3, h = bh & 7;
    const float* __restrict__ x = src ? kin : q;
    const float* xb = x + (size_t)b * 2097152u + (size_t)h * 64u + (size_t)(seg * 1024) * 512u;

    // staging: thread handles t-pair (tp,tp+1) and e-octet e0..e0+7
    const int tp = (tid & 31) * 2;
    const int e0 = (tid >> 5) * 8;

    const int wid = tid >> 6, lane = tid & 63;
    const int l15 = lane & 15, lg = lane >> 4;

    // A (twiddle) per-lane base: row = wid*32 + mt*16 + l15, k-base seg*1024 + 8*lg
    const size_t aOff = (size_t)(wid * 32 + l15) * 4096u + (size_t)(seg * 1024) + (size_t)(8 * lg);

    f32x4 acc[2][4];
#pragma unroll
    for (int mt = 0; mt < 2; ++mt)
#pragma unroll
        for (int nt = 0; nt < 4; ++nt)
            acc[mt][nt] = (f32x4){0.f, 0.f, 0.f, 0.f};

    float rs[16];
    {   // prologue: tile 0 loads
        const float* r0 = xb + (size_t)tp * 512u + e0;
        *(float4*)&rs[0]  = *(const float4*)r0;
        *(float4*)&rs[4]  = *(const float4*)(r0 + 4);
        *(float4*)&rs[8]  = *(const float4*)(r0 + 512);
        *(float4*)&rs[12] = *(const float4*)(r0 + 516);
    }

    for (int it = 0; it < 16; ++it) {
        // convert rs -> LDS (hi/lo packed pairs along t)
#pragma unroll
        for (int e = 0; e < 8; ++e) {
            const unsigned int hp = cvtpk(rs[e], rs[8 + e]);
            const float h0 = __builtin_bit_cast(float, hp << 16);
            const float h1 = __builtin_bit_cast(float, hp & 0xffff0000u);
            const unsigned int lp = cvtpk(rs[e] - h0, rs[8 + e] - h1);
            *(unsigned int*)&xTh[e0 + e][tp] = hp;
            *(unsigned int*)&xTl[e0 + e][tp] = lp;
        }
        __syncthreads();
        // issue next tile's global loads (land during MFMA phase)
        if (it + 1 < 16) {
            const float* r0 = xb + (size_t)((it + 1) * 64 + tp) * 512u + e0;
            *(float4*)&rs[0]  = *(const float4*)r0;
            *(float4*)&rs[4]  = *(const float4*)(r0 + 4);
            *(float4*)&rs[8]  = *(const float4*)(r0 + 512);
            *(float4*)&rs[12] = *(const float4*)(r0 + 516);
        }
#pragma unroll
        for (int ks = 0; ks < 2; ++ks) {
            const int koff = it * 64 + ks * 32;
            short8 Ah[2], Al[2];
#pragma unroll
            for (int mt = 0; mt < 2; ++mt) {
                Ah[mt] = *(const short8*)(Whi + aOff + (size_t)(mt * 16) * 4096u + koff);
                Al[mt] = *(const short8*)(Wlo + aOff + (size_t)(mt * 16) * 4096u + koff);
            }
            short8 Bh[4], Bl[4];
            const unsigned short* sh = &xTh[0][0];
            const unsigned short* sl = &xTl[0][0];
#pragma unroll
            for (int nt = 0; nt < 4; ++nt) {
                const int ri = (nt * 16 + l15) * 72 + 8 * lg + ks * 32;
                Bh[nt] = *(const short8*)(sh + ri);
                Bl[nt] = *(const short8*)(sl + ri);
            }
#pragma unroll
            for (int mt = 0; mt < 2; ++mt)
#pragma unroll
                for (int nt = 0; nt < 4; ++nt)
                    acc[mt][nt] = __builtin_amdgcn_mfma_f32_16x16x32_bf16(Ah[mt], Bh[nt], acc[mt][nt], 0, 0, 0);
#pragma unroll
            for (int mt = 0; mt < 2; ++mt)
#pragma unroll
                for (int nt = 0; nt < 4; ++nt)
                    acc[mt][nt] = __builtin_amdgcn_mfma_f32_16x16x32_bf16(Ah[mt], Bl[nt], acc[mt][nt], 0, 0, 0);
#pragma unroll
            for (int mt = 0; mt < 2; ++mt)
#pragma unroll
                for (int nt = 0; nt < 4; ++nt)
                    acc[mt][nt] = __builtin_amdgcn_mfma_f32_16x16x32_bf16(Al[mt], Bh[nt], acc[mt][nt], 0, 0, 0);
        }
        __syncthreads();
    }

    // C-write: X[e][row] (row 2m=Re, 2m+1=Im); seg 0 -> main, else partial set seg-1
    float* Xd;
    if (seg == 0) Xd = src ? Xk : Xq;
    else          Xd = (src ? Pk : Pq) + (size_t)(seg - 1) * 1048576u;
    Xd += (size_t)bh * 8192u;
#pragma unroll
    for (int mt = 0; mt < 2; ++mt)
#pragma unroll
        for (int nt = 0; nt < 4; ++nt) {
            const int e = nt * 16 + l15;
            const int r0 = wid * 32 + mt * 16 + 4 * lg;
            *(float4*)(Xd + (size_t)e * 128u + r0) = *(float4*)&acc[mt][nt];
        }
}

// ---------------- K1b: reduce the 3 K-split partial sets into main ----------------
__global__ __launch_bounds__(256) void k1_reduce(float* __restrict__ Xq, const float* __restrict__ Pq,
                                                 float* __restrict__ Xk, const float* __restrict__ Pk) {
    const int i = blockIdx.x * 256 + threadIdx.x;   // 262144 float4s per array
    float4* a = (float4*)Xq;
    float4* c = (float4*)Xk;
    float4 v = a[i], w = c[i];
#pragma unroll
    for (int s = 0; s < 3; ++s) {
        const float4 p = ((const float4*)(Pq + (size_t)s * 1048576u))[i];
        const float4 r = ((const float4*)(Pk + (size_t)s * 1048576u))[i];
        v.x += p.x; v.y += p.y; v.z += p.z; v.w += p.w;
        w.x += r.x; w.y += r.y; w.z += r.z; w.w += r.w;
    }
    a[i] = v;
    c[i] = w;
}

// ---------------- K2: xqk -> tanh -> xqkv -> *w ; writes XWT hi/lo bf16 [bh][o][128] ----------------
__global__ __launch_bounds__(256) void k2_mid(const float* __restrict__ Xq,
                                              const float* __restrict__ Xk,
                                              const float* __restrict__ w1,
                                              const float* __restrict__ w2,
                                              unsigned short* __restrict__ XWThi,
                                              unsigned short* __restrict__ XWTlo)
{
    const int bh = blockIdx.x;
    const int h = bh & 7;
    __shared__ float smem[12672];        // 50,688 B
    float* sA  = smem;                   // [16][66] complex (2112 floats)
    float* sB  = smem + 2112;            // [16][66] complex
    float* sPK = smem + 4224;            // [64][66] complex (8448 floats)

    const int tid = threadIdx.x;
    const float* Xqb = Xq + (size_t)bh * 8192u;
    const float* Xkb = Xk + (size_t)bh * 8192u;

    const int r  = tid >> 4;   // staging row 0..15
    const int f8 = tid & 15;   // staging 8-float group
    const int tx = tid & 15;   // P1: x = tx + 16*i
    const int ty = tid >> 4;   // P1: y = ty + 16*j

    // ---- P1: xqk[x][y] = sum_e Xq[e][x]*Xk[e][y] ----
    float aR[4][4] = {{0.f}}, aI[4][4] = {{0.f}};
    for (int ch = 0; ch < 4; ++ch) {
        {
            const float* gq = Xqb + (size_t)((ch * 16 + r) * 128 + f8 * 8);
            const float* gk = Xkb + (size_t)((ch * 16 + r) * 128 + f8 * 8);
            float* dA = sA + r * 132 + f8 * 8;
            float* dB = sB + r * 132 + f8 * 8;
            *(float4*)dA       = *(const float4*)gq;
            *(float4*)(dA + 4) = *(const float4*)(gq + 4);
            *(float4*)dB       = *(const float4*)gk;
            *(float4*)(dB + 4) = *(const float4*)(gk + 4);
        }
        __syncthreads();
        for (int er = 0; er < 16; ++er) {
            float2 qx[4], ky[4];
#pragma unroll
            for (int i = 0; i < 4; ++i) qx[i] = *(const float2*)(sA + er * 132 + (tx + 16 * i) * 2);
#pragma unroll
            for (int j = 0; j < 4; ++j) ky[j] = *(const float2*)(sB + er * 132 + (ty + 16 * j) * 2);
#pragma unroll
            for (int i = 0; i < 4; ++i)
#pragma unroll
                for (int j = 0; j < 4; ++j) {
                    aR[i][j] += qx[i].x * ky[j].x - qx[i].y * ky[j].y;
                    aI[i][j] += qx[i].x * ky[j].y + qx[i].y * ky[j].x;
                }
        }
        __syncthreads();
    }
#pragma unroll
    for (int i = 0; i < 4; ++i)
#pragma unroll
        for (int j = 0; j < 4; ++j) {
            const int xx = tx + 16 * i, yy = ty + 16 * j;
            *(float2*)(sPK + xx * 132 + yy * 2) = make_float2(tanhf(aR[i][j]), tanhf(aI[i][j]));
        }
    __syncthreads();

    // ---- P3+P4 per e-chunk ----
    float wR[4][4] = {{0.f}}, wI[4][4] = {{0.f}};   // [o-idx i][x-idx j]
    const int x16 = tid & 15, eo = tid >> 4;        // P3 mapping
    const int xg = tid & 15, og = tid >> 4;         // P4 mapping: x = 4*xg + j, o = og + 16*i
    for (int ch = 0; ch < 4; ++ch) {
        {   // stage LK chunk into sA
            const float* gk = Xkb + (size_t)((ch * 16 + r) * 128 + f8 * 8);
            float* dA = sA + r * 132 + f8 * 8;
            *(float4*)dA       = *(const float4*)gk;
            *(float4*)(dA + 4) = *(const float4*)(gk + 4);
        }
        __syncthreads();
        // P3: PV[eo][x16+16i] = sum_y PK[x][y]*LK[eo][y]
        {
            float pvR[4] = {0.f, 0.f, 0.f, 0.f}, pvI[4] = {0.f, 0.f, 0.f, 0.f};
            for (int y = 0; y < 64; ++y) {
                const float2 kv = *(const float2*)(sA + eo * 132 + y * 2);
#pragma unroll
                for (int i = 0; i < 4; ++i) {
                    const float2 p = *(const float2*)(sPK + (x16 + 16 * i) * 132 + y * 2);
                    pvR[i] += p.x * kv.x - p.y * kv.y;
                    pvI[i] += p.x * kv.y + p.y * kv.x;
                }
            }
#pragma unroll
            for (int i = 0; i < 4; ++i)
                *(float2*)(sB + eo * 132 + (x16 + 16 * i) * 2) = make_float2(pvR[i], pvI[i]);
        }
        __syncthreads();
        // P4: wacc[o][x] += sum_{e in chunk} PV[e][x] * (w1 + i*w2)[h][e][o][x]
        for (int el = 0; el < 16; ++el) {
            const int e = ch * 16 + el;
            float2 pv[4];
#pragma unroll
            for (int jp = 0; jp < 2; ++jp) {
                const float4 t = *(const float4*)(sB + el * 132 + xg * 8 + jp * 4);
                pv[2 * jp]     = make_float2(t.x, t.y);
                pv[2 * jp + 1] = make_float2(t.z, t.w);
            }
            const float* w1p = w1 + (size_t)(((h * 64 + e) * 64 + og) * 64 + xg * 4);
            const float* w2p = w2 + (size_t)(((h * 64 + e) * 64 + og) * 64 + xg * 4);
#pragma unroll
            for (int i = 0; i < 4; ++i) {
                const float4 w1v = *(const float4*)(w1p + i * 1024);
                const float4 w2v = *(const float4*)(w2p + i * 1024);
                const float w1a[4] = {w1v.x, w1v.y, w1v.z, w1v.w};
                const float w2a[4] = {w2v.x, w2v.y, w2v.z, w2v.w};
#pragma unroll
                for (int j = 0; j < 4; ++j) {
                    wR[i][j] += pv[j].x * w1a[j] - pv[j].y * w2a[j];
                    wI[i][j] += pv[j].x * w2a[j] + pv[j].y * w1a[j];
                }
            }
        }
        __syncthreads();
    }
    // write XWT [bh][o][k=128]: col 2x = Re, 2x+1 = Im; hi and lo bf16
    unsigned short* Th = XWThi + (size_t)bh * 8192u;
    unsigned short* Tl = XWTlo + (size_t)bh * 8192u;
#pragma unroll
    for (int i = 0; i < 4; ++i) {
        const int o = og + 16 * i;
        unsigned int hp[4], lp[4];
#pragma unroll
        for (int j = 0; j < 4; ++j) {
            hp[j] = cvtpk(wR[i][j], wI[i][j]);
            const float hR = __builtin_bit_cast(float, hp[j] << 16);
            const float hI = __builtin_bit_cast(float, hp[j] & 0xffff0000u);
            lp[j] = cvtpk(wR[i][j] - hR, wI[i][j] - hI);
        }
        *(uint4*)(Th + (size_t)o * 128u + xg * 8) = make_uint4(hp[0], hp[1], hp[2], hp[3]);
        *(uint4*)(Tl + (size_t)o * 128u + xg * 8) = make_uint4(lp[0], lp[1], lp[2], lp[3]);
    }
}

// ---------------- K3: MFMA irfft  out[4096t x 64o] = basis[4096x128] * XWT^T ----------------
__global__ __launch_bounds__(256, 3) void k3_mfma(const unsigned short* __restrict__ basis,
                                                  const unsigned short* __restrict__ XWThi,
                                                  const unsigned short* __restrict__ XWTlo,
                                                  float* __restrict__ out)
{
    const int bid = blockIdx.x;
    const int bh = bid >> 4, tc = bid & 15;
    const int b = bh >> 3, h = bh & 7;
    const int tid = threadIdx.x;
    const int wid = tid >> 6, lane = tid & 63;
    const int l15 = lane & 15, lg = lane >> 4;

    const int t0 = tc * 256 + wid * 64;     // wave's 64 t-rows
    const unsigned short* Th = XWThi + (size_t)bh * 8192u;
    const unsigned short* Tl = XWTlo + (size_t)bh * 8192u;

    f32x4 acc[4][4];
#pragma unroll
    for (int mt = 0; mt < 4; ++mt)
#pragma unroll
        for (int nt = 0; nt < 4; ++nt)
            acc[mt][nt] = (f32x4){0.f, 0.f, 0.f, 0.f};

#pragma unroll
    for (int ks = 0; ks < 4; ++ks) {
        const int ko = ks * 32 + 8 * lg;
        short8 A[4], Bh[4], Bl[4];
#pragma unroll
        for (int mt = 0; mt < 4; ++mt)
            A[mt] = *(const short8*)(basis + (size_t)(t0 + mt * 16 + l15) * 128u + ko);
#pragma unroll
        for (int nt = 0; nt < 4; ++nt) {
            Bh[nt] = *(const short8*)(Th + (size_t)(nt * 16 + l15) * 128u + ko);
            Bl[nt] = *(const short8*)(Tl + (size_t)(nt * 16 + l15) * 128u + ko);
        }
#pragma unroll
        for (int mt = 0; mt < 4; ++mt)
#pragma unroll
            for (int nt = 0; nt < 4; ++nt)
                acc[mt][nt] = __builtin_amdgcn_mfma_f32_16x16x32_bf16(A[mt], Bh[nt], acc[mt][nt], 0, 0, 0);
#pragma unroll
        for (int mt = 0; mt < 4; ++mt)
#pragma unroll
            for (int nt = 0; nt < 4; ++nt)
                acc[mt][nt] = __builtin_amdgcn_mfma_f32_16x16x32_bf16(A[mt], Bl[nt], acc[mt][nt], 0, 0, 0);
    }

    const float scale = 9.313225746154785e-10f;  // 2^-30 = (1/4096) * (1/262144)
#pragma unroll
    for (int mt = 0; mt < 4; ++mt)
#pragma unroll
        for (int nt = 0; nt < 4; ++nt) {
            const int o = nt * 16 + l15;
#pragma unroll
            for (int j = 0; j < 4; ++j) {
                const int t = t0 + mt * 16 + 4 * lg + j;
                out[((size_t)(b * 4096 + t) * 8u + (size_t)h) * 64u + o] = acc[mt][nt][j] * scale;
            }
        }
}

extern "C" void kernel_launch(void* const* d_in, const int* in_sizes, int n_in,
                              void* d_out, int out_size, void* d_ws, size_t ws_size,
                              hipStream_t stream) {
    (void)in_sizes; (void)n_in; (void)out_size; (void)ws_size;
    const float* q  = (const float*)d_in[0];
    const float* k  = (const float*)d_in[1];
    // d_in[2] = v: unused by the reference forward
    const float* w1 = (const float*)d_in[3];
    const float* w2 = (const float*)d_in[4];
    float* out = (float*)d_out;

    // ws (proven >= 12 MB): Xq [0,1M) fl, Xk [1M,2M) fl, XWThi/Tlo [2M,3M) fl as bf16
    float* ws = (float*)d_ws;
    float* Xq = ws;
    float* Xk = ws + 1048576;
    unsigned short* XWThi = (unsigned short*)(ws + 2097152);   // 1,048,576 shorts
    unsigned short* XWTlo = XWThi + 1048576;
    unsigned short* basis = (unsigned short*)ws;               // overlays Xq AFTER k2

    // d_out scratch (dead before k3 overwrites): W tables + K-split partials
    unsigned short* Whi = (unsigned short*)out;                // 524,288 shorts
    unsigned short* Wlo = Whi + 524288;                        // floats [262144, 524288)
    float* Pq = out + 524288;                                  // 3 x 1,048,576 floats
    float* Pk = out + 3670016;                                 // 3 x 1,048,576 floats

    hipLaunchKernelGGL(k0_twiddle, dim3(512),  dim3(256), 0, stream, Whi, Wlo);
    hipLaunchKernelGGL(k1_mfma,    dim3(1024), dim3(256), 0, stream, q, k, Whi, Wlo, Xq, Xk, Pq, Pk);
    hipLaunchKernelGGL(k1_reduce,  dim3(1024), dim3(256), 0, stream, Xq, Pq, Xk, Pk);
    hipLaunchKernelGGL(k2_mid,     dim3(128),  dim3(256), 0, stream, Xq, Xk, w1, w2, XWThi, XWTlo);
    hipLaunchKernelGGL(k0_basis,   dim3(256),  dim3(256), 0, stream, basis);
    hipLaunchKernelGGL(k3_mfma,    dim3(2048), dim3(256), 0, stream, basis, XWThi, XWTlo, out);
}

// Round 4
// 244.336 us; speedup vs baseline: 2.2677x; 1.4658x over previous
//
#include <hip/hip_runtime.h>
#include <math.h>

// FourierCrossAttention: B=16, L=4096, H=8, E=EO=64, MODES=64 (lowest)
// R4: k2_mid (170us, latency-bound monolith) split into 4 parallel fp32 kernels:
//   k2a: P1 xqk=Xq^T.Xk + tanh  -> P [bh][y][2x]        (512 blocks)
//   k2b: P3 PV = P . Xk         -> PVG[h][m][c][b][e]    (512 blocks)
//   kwt: w1/w2 -> wT[h][m][e][2o] transpose              (512 blocks)
//   k2c: P4 XW = PV . w         -> XWT hi/lo bf16        (512 blocks)
// k1/k3 MFMA paths unchanged from R3.

constexpr float TWOPI_L = 1.5339807878856412e-3f;  // 2*pi/4096

typedef __attribute__((ext_vector_type(8))) short short8;
typedef __attribute__((ext_vector_type(4))) float f32x4;

__device__ __forceinline__ unsigned short f2bf(float f) {
    unsigned int u = __builtin_bit_cast(unsigned int, f);
    unsigned int r = (u + 0x7fffu + ((u >> 16) & 1u)) >> 16;
    return (unsigned short)r;
}
__device__ __forceinline__ float bf2f(unsigned short h) {
    unsigned int u = ((unsigned int)h) << 16;
    return __builtin_bit_cast(float, u);
}
// packed RNE f32->bf16 pair: low16 = bf(a), high16 = bf(b)
__device__ __forceinline__ unsigned int cvtpk(float a, float b) {
    unsigned int r;
    asm("v_cvt_pk_bf16_f32 %0, %1, %2" : "=v"(r) : "v"(a), "v"(b));
    return r;
}

// ---------------- K0: DFT twiddle tables (hi/lo bf16) ----------------
__global__ __launch_bounds__(256) void k0_twiddle(unsigned short* __restrict__ Whi,
                                                  unsigned short* __restrict__ Wlo) {
    const int idx = blockIdx.x * 256 + threadIdx.x;   // 131072 threads
    const int r = idx >> 10;            // 0..127
    const int t4 = (idx & 1023) << 2;   // 0..4092
    const int m = r >> 1;
    const bool isim = (r & 1) != 0;
#pragma unroll
    for (int j = 0; j < 4; ++j) {
        const int t = t4 + j;
        float sv, cv;
        sincosf((float)((m * t) & 4095) * TWOPI_L, &sv, &cv);
        const float v = isim ? -sv : cv;
        const unsigned short hi = f2bf(v);
        const unsigned short lo = f2bf(v - bf2f(hi));
        Whi[r * 4096 + t] = hi;
        Wlo[r * 4096 + t] = lo;
    }
}

// ---------------- K0b: irfft basis (bf16 hi only), written into ws (ex-Xq) ----------------
__global__ __launch_bounds__(256) void k0_basis(unsigned short* __restrict__ basis) {
    const int idx = blockIdx.x * 256 + threadIdx.x;   // 65536 threads x 4 pairs
    const int p0 = idx << 2;                          // (t,m) pair index
    const int t = p0 >> 6;
    unsigned int pk[4];
#pragma unroll
    for (int j = 0; j < 4; ++j) {
        const int m = (p0 & 63) + j;
        float sv, cv;
        sincosf((float)((m * t) & 4095) * TWOPI_L, &sv, &cv);
        const float c = (m == 0) ? 1.0f : 2.0f * cv;
        const float s = (m == 0) ? 0.0f : -2.0f * sv;
        pk[j] = (unsigned int)f2bf(c) | ((unsigned int)f2bf(s) << 16);
    }
    *(uint4*)(basis + (size_t)t * 128u + ((p0 & 63) << 1)) =
        make_uint4(pk[0], pk[1], pk[2], pk[3]);
}

// ---------------- K1: MFMA DFT  C[128 rows][64 e], K=1024 per block (S=4) ----------------
__global__ __launch_bounds__(256, 3) void k1_mfma(const float* __restrict__ q,
                                                  const float* __restrict__ kin,
                                                  const unsigned short* __restrict__ Whi,
                                                  const unsigned short* __restrict__ Wlo,
                                                  float* __restrict__ Xq, float* __restrict__ Xk,
                                                  float* __restrict__ Pq, float* __restrict__ Pk)
{
    __shared__ unsigned short xTh[64][72];   // [e][k pad 64+8] hi, single buffer
    __shared__ unsigned short xTl[64][72];   // lo   (36,864 B total)

    const int tid = threadIdx.x;
    const int bid = blockIdx.x;
    const int bh = bid >> 3, src = (bid >> 2) & 1, seg = bid & 3;
    const int b = bh >> 3, h = bh & 7;
    const float* __restrict__ x = src ? kin : q;
    const float* xb = x + (size_t)b * 2097152u + (size_t)h * 64u + (size_t)(seg * 1024) * 512u;

    const int tp = (tid & 31) * 2;
    const int e0 = (tid >> 5) * 8;

    const int wid = tid >> 6, lane = tid & 63;
    const int l15 = lane & 15, lg = lane >> 4;

    const size_t aOff = (size_t)(wid * 32 + l15) * 4096u + (size_t)(seg * 1024) + (size_t)(8 * lg);

    f32x4 acc[2][4];
#pragma unroll
    for (int mt = 0; mt < 2; ++mt)
#pragma unroll
        for (int nt = 0; nt < 4; ++nt)
            acc[mt][nt] = (f32x4){0.f, 0.f, 0.f, 0.f};

    float rs[16];
    {   // prologue: tile 0 loads
        const float* r0 = xb + (size_t)tp * 512u + e0;
        *(float4*)&rs[0]  = *(const float4*)r0;
        *(float4*)&rs[4]  = *(const float4*)(r0 + 4);
        *(float4*)&rs[8]  = *(const float4*)(r0 + 512);
        *(float4*)&rs[12] = *(const float4*)(r0 + 516);
    }

    for (int it = 0; it < 16; ++it) {
#pragma unroll
        for (int e = 0; e < 8; ++e) {
            const unsigned int hp = cvtpk(rs[e], rs[8 + e]);
            const float h0 = __builtin_bit_cast(float, hp << 16);
            const float h1 = __builtin_bit_cast(float, hp & 0xffff0000u);
            const unsigned int lp = cvtpk(rs[e] - h0, rs[8 + e] - h1);
            *(unsigned int*)&xTh[e0 + e][tp] = hp;
            *(unsigned int*)&xTl[e0 + e][tp] = lp;
        }
        __syncthreads();
        if (it + 1 < 16) {
            const float* r0 = xb + (size_t)((it + 1) * 64 + tp) * 512u + e0;
            *(float4*)&rs[0]  = *(const float4*)r0;
            *(float4*)&rs[4]  = *(const float4*)(r0 + 4);
            *(float4*)&rs[8]  = *(const float4*)(r0 + 512);
            *(float4*)&rs[12] = *(const float4*)(r0 + 516);
        }
#pragma unroll
        for (int ks = 0; ks < 2; ++ks) {
            const int koff = it * 64 + ks * 32;
            short8 Ah[2], Al[2];
#pragma unroll
            for (int mt = 0; mt < 2; ++mt) {
                Ah[mt] = *(const short8*)(Whi + aOff + (size_t)(mt * 16) * 4096u + koff);
                Al[mt] = *(const short8*)(Wlo + aOff + (size_t)(mt * 16) * 4096u + koff);
            }
            short8 Bh[4], Bl[4];
            const unsigned short* sh = &xTh[0][0];
            const unsigned short* sl = &xTl[0][0];
#pragma unroll
            for (int nt = 0; nt < 4; ++nt) {
                const int ri = (nt * 16 + l15) * 72 + 8 * lg + ks * 32;
                Bh[nt] = *(const short8*)(sh + ri);
                Bl[nt] = *(const short8*)(sl + ri);
            }
#pragma unroll
            for (int mt = 0; mt < 2; ++mt)
#pragma unroll
                for (int nt = 0; nt < 4; ++nt)
                    acc[mt][nt] = __builtin_amdgcn_mfma_f32_16x16x32_bf16(Ah[mt], Bh[nt], acc[mt][nt], 0, 0, 0);
#pragma unroll
            for (int mt = 0; mt < 2; ++mt)
#pragma unroll
                for (int nt = 0; nt < 4; ++nt)
                    acc[mt][nt] = __builtin_amdgcn_mfma_f32_16x16x32_bf16(Ah[mt], Bl[nt], acc[mt][nt], 0, 0, 0);
#pragma unroll
            for (int mt = 0; mt < 2; ++mt)
#pragma unroll
                for (int nt = 0; nt < 4; ++nt)
                    acc[mt][nt] = __builtin_amdgcn_mfma_f32_16x16x32_bf16(Al[mt], Bh[nt], acc[mt][nt], 0, 0, 0);
        }
        __syncthreads();
    }

    float* Xd;
    if (seg == 0) Xd = src ? Xk : Xq;
    else          Xd = (src ? Pk : Pq) + (size_t)(seg - 1) * 1048576u;
    Xd += (size_t)bh * 8192u;
#pragma unroll
    for (int mt = 0; mt < 2; ++mt)
#pragma unroll
        for (int nt = 0; nt < 4; ++nt) {
            const int e = nt * 16 + l15;
            const int r0 = wid * 32 + mt * 16 + 4 * lg;
            *(float4*)(Xd + (size_t)e * 128u + r0) = *(float4*)&acc[mt][nt];
        }
}

// ---------------- K1b: reduce the 3 K-split partial sets into main ----------------
__global__ __launch_bounds__(256) void k1_reduce(float* __restrict__ Xq, const float* __restrict__ Pq,
                                                 float* __restrict__ Xk, const float* __restrict__ Pk) {
    const int i = blockIdx.x * 256 + threadIdx.x;   // 262144 float4s per array
    float4* a = (float4*)Xq;
    float4* c = (float4*)Xk;
    float4 v = a[i], w = c[i];
#pragma unroll
    for (int s = 0; s < 3; ++s) {
        const float4 p = ((const float4*)(Pq + (size_t)s * 1048576u))[i];
        const float4 r = ((const float4*)(Pk + (size_t)s * 1048576u))[i];
        v.x += p.x; v.y += p.y; v.z += p.z; v.w += p.w;
        w.x += r.x; w.y += r.y; w.z += r.z; w.w += r.w;
    }
    a[i] = v;
    c[i] = w;
}

// ---------------- K2a: P1  xqk = Xq^T . Xk (complex), tanh -> P[bh][y][2x] ----------------
__global__ __launch_bounds__(256) void k2a_p1(const float* __restrict__ Xq,
                                              const float* __restrict__ Xk,
                                              float* __restrict__ P)
{
    const int blk = blockIdx.x;
    const int bh = blk >> 2, xt = blk & 3;
    __shared__ float sQ[64 * 32];    // [e][2x-slice]
    __shared__ float sK[64 * 128];   // [e][2y]
    const int tid = threadIdx.x;
    const float* Xqb = Xq + (size_t)bh * 8192u;
    const float* Xkb = Xk + (size_t)bh * 8192u;

#pragma unroll
    for (int p = 0; p < 2; ++p) {
        const int f4 = tid + p * 256;           // 512 float4s
        const int row = f4 >> 3, c4 = f4 & 7;
        *(float4*)&sQ[row * 32 + c4 * 4] = *(const float4*)(Xqb + row * 128 + xt * 32 + c4 * 4);
    }
#pragma unroll
    for (int p = 0; p < 8; ++p) {
        const int f4 = tid + p * 256;           // 2048 float4s
        *(float4*)&sK[f4 * 4] = *(const float4*)(Xkb + f4 * 4);
    }
    __syncthreads();

    const int xg = tid & 15, yg = tid >> 4;
    float aR[4] = {0.f, 0.f, 0.f, 0.f}, aI[4] = {0.f, 0.f, 0.f, 0.f};
#pragma unroll 8
    for (int e = 0; e < 64; ++e) {
        const float2 qv = *(const float2*)&sQ[e * 32 + 2 * xg];
        const float4 k0 = *(const float4*)&sK[e * 128 + 8 * yg];
        const float4 k1v = *(const float4*)&sK[e * 128 + 8 * yg + 4];
        aR[0] += qv.x * k0.x - qv.y * k0.y;   aI[0] += qv.x * k0.y + qv.y * k0.x;
        aR[1] += qv.x * k0.z - qv.y * k0.w;   aI[1] += qv.x * k0.w + qv.y * k0.z;
        aR[2] += qv.x * k1v.x - qv.y * k1v.y; aI[2] += qv.x * k1v.y + qv.y * k1v.x;
        aR[3] += qv.x * k1v.z - qv.y * k1v.w; aI[3] += qv.x * k1v.w + qv.y * k1v.z;
    }
    float* Pb = P + (size_t)bh * 8192u;
    const int x_abs = xt * 16 + xg;
#pragma unroll
    for (int j = 0; j < 4; ++j) {
        const int y = 4 * yg + j;
        *(float2*)(Pb + (size_t)y * 128u + 2 * x_abs) =
            make_float2(tanhf(aR[j]), tanhf(aI[j]));
    }
}

// ---------------- K2b: P3  PV = P . Xk (complex over y) -> PVG[h][m][c][b][e] ----------------
__global__ __launch_bounds__(256) void k2b_p3(const float* __restrict__ P,
                                              const float* __restrict__ Xk,
                                              float* __restrict__ PVG)
{
    const int blk = blockIdx.x;
    const int bh = blk >> 2, et = blk & 3;
    const int b = bh >> 3, h = bh & 7;
    __shared__ float sP[64 * 128];   // [y][2x]
    __shared__ float sKe[16 * 132];  // [e_loc][2y] pad->132 (breaks 4-way bank alias)
    const int tid = threadIdx.x;
    const float* Pb = P + (size_t)bh * 8192u;
    const float* Xkb = Xk + (size_t)bh * 8192u + (size_t)(et * 16) * 128u;

#pragma unroll
    for (int p = 0; p < 8; ++p) {
        const int f4 = tid + p * 256;
        *(float4*)&sP[f4 * 4] = *(const float4*)(Pb + f4 * 4);
    }
#pragma unroll
    for (int p = 0; p < 2; ++p) {
        const int f4 = tid + p * 256;           // 512 float4s
        const int row = f4 >> 5, c4 = f4 & 31;
        *(float4*)&sKe[row * 132 + c4 * 4] = *(const float4*)(Xkb + row * 128 + c4 * 4);
    }
    __syncthreads();

    const int xg = tid & 15, el = tid >> 4;
    float aR[4] = {0.f, 0.f, 0.f, 0.f}, aI[4] = {0.f, 0.f, 0.f, 0.f};
#pragma unroll 8
    for (int y = 0; y < 64; ++y) {
        const float2 kv = *(const float2*)&sKe[el * 132 + 2 * y];
        const float4 p0 = *(const float4*)&sP[y * 128 + 8 * xg];
        const float4 p1 = *(const float4*)&sP[y * 128 + 8 * xg + 4];
        aR[0] += p0.x * kv.x - p0.y * kv.y;   aI[0] += p0.x * kv.y + p0.y * kv.x;
        aR[1] += p0.z * kv.x - p0.w * kv.y;   aI[1] += p0.z * kv.y + p0.w * kv.x;
        aR[2] += p1.x * kv.x - p1.y * kv.y;   aI[2] += p1.x * kv.y + p1.y * kv.x;
        aR[3] += p1.z * kv.x - p1.w * kv.y;   aI[3] += p1.z * kv.y + p1.w * kv.x;
    }
    const int e_abs = et * 16 + el;
    float* base = PVG + (size_t)h * 131072u;   // per h: 64m*2c*16b*64e
#pragma unroll
    for (int j = 0; j < 4; ++j) {
        const int m = 4 * xg + j;
        base[(size_t)m * 2048u + 0u    + (size_t)b * 64u + e_abs] = aR[j];
        base[(size_t)m * 2048u + 1024u + (size_t)b * 64u + e_abs] = aI[j];
    }
}

// ---------------- KWT: w1/w2 -> wT[h][m][e][2o] ----------------
__global__ __launch_bounds__(256) void kwt(const float* __restrict__ w1,
                                           const float* __restrict__ w2,
                                           float* __restrict__ wT)
{
    const int blk = blockIdx.x;     // h*64 + e
    const int h = blk >> 6, e = blk & 63;
    const int tid = threadIdx.x;
    const int m = tid & 63, oq = tid >> 6;   // o = oq*16 + i
    const float* w1b = w1 + ((size_t)(h * 64 + e)) * 4096u;
    const float* w2b = w2 + ((size_t)(h * 64 + e)) * 4096u;
    float buf[32];
#pragma unroll
    for (int i = 0; i < 16; ++i) {
        const int o = oq * 16 + i;
        buf[2 * i]     = w1b[o * 64 + m];
        buf[2 * i + 1] = w2b[o * 64 + m];
    }
    float* dst = wT + (((size_t)(h * 64 + m)) * 64u + e) * 128u + oq * 32;
#pragma unroll
    for (int i = 0; i < 8; ++i)
        *(float4*)(dst + i * 4) = *(float4*)&buf[i * 4];
}

// ---------------- K2c: P4  XW = PV . (w1 + i w2) -> XWT hi/lo bf16 ----------------
__global__ __launch_bounds__(256) void k2c_p4(const float* __restrict__ PVG,
                                              const float* __restrict__ wT,
                                              unsigned short* __restrict__ XWThi,
                                              unsigned short* __restrict__ XWTlo)
{
    const int blk = blockIdx.x;       // h*64 + m
    const int h = blk >> 6, m = blk & 63;
    __shared__ float sA[32 * 68];     // [c*16+b][e pad 68]
    __shared__ float sW[64 * 128];    // [e][2o]
    const int tid = threadIdx.x;
    const float* Ab = PVG + (size_t)h * 131072u + (size_t)m * 2048u;
    const float* Wb = wT + ((size_t)h * 64u + m) * 8192u;

#pragma unroll
    for (int p = 0; p < 2; ++p) {
        const int f4 = tid + p * 256;           // 512 float4s
        const int row = f4 >> 4, e0 = (f4 & 15) * 4;
        *(float4*)&sA[row * 68 + e0] = *(const float4*)(Ab + row * 64 + e0);
    }
#pragma unroll
    for (int p = 0; p < 8; ++p) {
        const int f4 = tid + p * 256;
        *(float4*)&sW[f4 * 4] = *(const float4*)(Wb + f4 * 4);
    }
    __syncthreads();

    const int og = tid & 15, b = tid >> 4;
    float aR[4] = {0.f, 0.f, 0.f, 0.f}, aI[4] = {0.f, 0.f, 0.f, 0.f};
#pragma unroll 8
    for (int e = 0; e < 64; ++e) {
        const float pR = sA[b * 68 + e];
        const float pI = sA[(16 + b) * 68 + e];
        const float4 w0 = *(const float4*)&sW[e * 128 + 8 * og];
        const float4 w1v = *(const float4*)&sW[e * 128 + 8 * og + 4];
        aR[0] += pR * w0.x - pI * w0.y;   aI[0] += pR * w0.y + pI * w0.x;
        aR[1] += pR * w0.z - pI * w0.w;   aI[1] += pR * w0.w + pI * w0.z;
        aR[2] += pR * w1v.x - pI * w1v.y; aI[2] += pR * w1v.y + pI * w1v.x;
        aR[3] += pR * w1v.z - pI * w1v.w; aI[3] += pR * w1v.w + pI * w1v.z;
    }
    const int bh = b * 8 + h;
    unsigned short* Th = XWThi + (size_t)bh * 8192u;
    unsigned short* Tl = XWTlo + (size_t)bh * 8192u;
#pragma unroll
    for (int j = 0; j < 4; ++j) {
        const int o = 4 * og + j;
        const unsigned int hp = cvtpk(aR[j], aI[j]);
        const float hR = __builtin_bit_cast(float, hp << 16);
        const float hI = __builtin_bit_cast(float, hp & 0xffff0000u);
        const unsigned int lp = cvtpk(aR[j] - hR, aI[j] - hI);
        *(unsigned int*)(Th + (size_t)o * 128u + 2 * m) = hp;
        *(unsigned int*)(Tl + (size_t)o * 128u + 2 * m) = lp;
    }
}

// ---------------- K3: MFMA irfft  out[4096t x 64o] = basis[4096x128] * XWT^T ----------------
__global__ __launch_bounds__(256, 3) void k3_mfma(const unsigned short* __restrict__ basis,
                                                  const unsigned short* __restrict__ XWThi,
                                                  const unsigned short* __restrict__ XWTlo,
                                                  float* __restrict__ out)
{
    const int bid = blockIdx.x;
    const int bh = bid >> 4, tc = bid & 15;
    const int b = bh >> 3, h = bh & 7;
    const int tid = threadIdx.x;
    const int wid = tid >> 6, lane = tid & 63;
    const int l15 = lane & 15, lg = lane >> 4;

    const int t0 = tc * 256 + wid * 64;
    const unsigned short* Th = XWThi + (size_t)bh * 8192u;
    const unsigned short* Tl = XWTlo + (size_t)bh * 8192u;

    f32x4 acc[4][4];
#pragma unroll
    for (int mt = 0; mt < 4; ++mt)
#pragma unroll
        for (int nt = 0; nt < 4; ++nt)
            acc[mt][nt] = (f32x4){0.f, 0.f, 0.f, 0.f};

#pragma unroll
    for (int ks = 0; ks < 4; ++ks) {
        const int ko = ks * 32 + 8 * lg;
        short8 A[4], Bh[4], Bl[4];
#pragma unroll
        for (int mt = 0; mt < 4; ++mt)
            A[mt] = *(const short8*)(basis + (size_t)(t0 + mt * 16 + l15) * 128u + ko);
#pragma unroll
        for (int nt = 0; nt < 4; ++nt) {
            Bh[nt] = *(const short8*)(Th + (size_t)(nt * 16 + l15) * 128u + ko);
            Bl[nt] = *(const short8*)(Tl + (size_t)(nt * 16 + l15) * 128u + ko);
        }
#pragma unroll
        for (int mt = 0; mt < 4; ++mt)
#pragma unroll
            for (int nt = 0; nt < 4; ++nt)
                acc[mt][nt] = __builtin_amdgcn_mfma_f32_16x16x32_bf16(A[mt], Bh[nt], acc[mt][nt], 0, 0, 0);
#pragma unroll
        for (int mt = 0; mt < 4; ++mt)
#pragma unroll
            for (int nt = 0; nt < 4; ++nt)
                acc[mt][nt] = __builtin_amdgcn_mfma_f32_16x16x32_bf16(A[mt], Bl[nt], acc[mt][nt], 0, 0, 0);
    }

    const float scale = 9.313225746154785e-10f;  // 2^-30
#pragma unroll
    for (int mt = 0; mt < 4; ++mt)
#pragma unroll
        for (int nt = 0; nt < 4; ++nt) {
            const int o = nt * 16 + l15;
#pragma unroll
            for (int j = 0; j < 4; ++j) {
                const int t = t0 + mt * 16 + 4 * lg + j;
                out[((size_t)(b * 4096 + t) * 8u + (size_t)h) * 64u + o] = acc[mt][nt][j] * scale;
            }
        }
}

extern "C" void kernel_launch(void* const* d_in, const int* in_sizes, int n_in,
                              void* d_out, int out_size, void* d_ws, size_t ws_size,
                              hipStream_t stream) {
    (void)in_sizes; (void)n_in; (void)out_size; (void)ws_size;
    const float* q  = (const float*)d_in[0];
    const float* k  = (const float*)d_in[1];
    // d_in[2] = v: unused by the reference forward
    const float* w1 = (const float*)d_in[3];
    const float* w2 = (const float*)d_in[4];
    float* out = (float*)d_out;

    // ws (12 MB): Xq [0,4MB) fl, Xk [4,8MB) fl, XWThi/lo [8,12MB) as bf16
    float* ws = (float*)d_ws;
    float* Xq = ws;
    float* Xk = ws + 1048576;
    unsigned short* XWThi = (unsigned short*)(ws + 2097152);   // 1,048,576 shorts
    unsigned short* XWTlo = XWThi + 1048576;
    unsigned short* basis = (unsigned short*)ws;               // overlays Xq AFTER k2a

    // d_out scratch (128 MB; all regions dead before k3 overwrites):
    unsigned short* Whi = (unsigned short*)out;                // [0, 262144) fl
    unsigned short* Wlo = Whi + 524288;                        // [262144, 524288) fl
    float* Pq  = out + 524288;                                 // 3 x 1M fl
    float* Pk  = out + 3670016;                                // 3 x 1M fl -> ends 6,815,744
    float* P   = out + 8388608;                                // 1M fl  (tanh'd xqk, [y][2x])
    float* wT  = out + 12582912;                               // 4M fl  [h][m][e][2o]
    float* PVG = out + 16777216;                               // 1M fl  [h][m][c][b][e]

    hipLaunchKernelGGL(k0_twiddle, dim3(512),  dim3(256), 0, stream, Whi, Wlo);
    hipLaunchKernelGGL(k1_mfma,    dim3(1024), dim3(256), 0, stream, q, k, Whi, Wlo, Xq, Xk, Pq, Pk);
    hipLaunchKernelGGL(k1_reduce,  dim3(1024), dim3(256), 0, stream, Xq, Pq, Xk, Pk);
    hipLaunchKernelGGL(k2a_p1,     dim3(512),  dim3(256), 0, stream, Xq, Xk, P);
    hipLaunchKernelGGL(k0_basis,   dim3(256),  dim3(256), 0, stream, basis);
    hipLaunchKernelGGL(k2b_p3,     dim3(512),  dim3(256), 0, stream, P, Xk, PVG);
    hipLaunchKernelGGL(kwt,        dim3(512),  dim3(256), 0, stream, w1, w2, wT);
    hipLaunchKernelGGL(k2c_p4,     dim3(512),  dim3(256), 0, stream, PVG, wT, XWThi, XWTlo);
    hipLaunchKernelGGL(k3_mfma,    dim3(2048), dim3(256), 0, stream, basis, XWThi, XWTlo, out);
}